// Round 1
// baseline (102.713 us; speedup 1.0000x reference)
//
#include <hip/hip_runtime.h>

#define LAMBDA_NOOBJ 0.5f
#define LAMBDA_COORD 5.0f

// Each thread processes GROUP=4 cells (= 20 floats = five aligned float4 loads
// per input). Per-thread partial sums -> wave shfl reduce -> LDS cross-wave ->
// one atomicAdd per block per accumulator.
__global__ __launch_bounds__(256) void yolo_loss_kernel(
    const float* __restrict__ pred,
    const float* __restrict__ targ,
    float* __restrict__ out,        // out[1]=box, out[2]=obj, out[3]=noobj
    int ngroups, int ncells) {
  float box = 0.f, obj = 0.f, noobj = 0.f;
  const int tid = blockIdx.x * blockDim.x + threadIdx.x;
  const int stride = gridDim.x * blockDim.x;

  for (int g = tid; g < ngroups; g += stride) {
    const float4* p4 = reinterpret_cast<const float4*>(pred + (size_t)g * 20);
    const float4* t4 = reinterpret_cast<const float4*>(targ + (size_t)g * 20);
    float p[20], t[20];
#pragma unroll
    for (int i = 0; i < 5; ++i) {
      float4 a = p4[i];
      float4 b = t4[i];
      p[i * 4 + 0] = a.x; p[i * 4 + 1] = a.y; p[i * 4 + 2] = a.z; p[i * 4 + 3] = a.w;
      t[i * 4 + 0] = b.x; t[i * 4 + 1] = b.y; t[i * 4 + 2] = b.z; t[i * 4 + 3] = b.w;
    }
#pragma unroll
    for (int c = 0; c < 4; ++c) {
      float c_t = t[c * 5];
      float cd = c_t - p[c * 5];
      cd *= cd;
      float bd = 0.f;
#pragma unroll
      for (int k = 1; k < 5; ++k) {
        float d = t[c * 5 + k] - p[c * 5 + k];
        bd += d * d;
      }
      bool is_obj = (c_t == 1.0f);
      box += is_obj ? bd : 0.f;
      obj += is_obj ? cd : 0.f;
      noobj += is_obj ? 0.f : cd;
    }
  }

  // Tail cells (ncells not divisible by 4) — handled by the first few threads.
  const int tail_start = ngroups * 4;
  for (int c = tail_start + tid; c < ncells; c += stride) {
    const float* pc = pred + (size_t)c * 5;
    const float* tc = targ + (size_t)c * 5;
    float c_t = tc[0];
    float cd = c_t - pc[0];
    cd *= cd;
    float bd = 0.f;
#pragma unroll
    for (int k = 1; k < 5; ++k) {
      float d = tc[k] - pc[k];
      bd += d * d;
    }
    bool is_obj = (c_t == 1.0f);
    box += is_obj ? bd : 0.f;
    obj += is_obj ? cd : 0.f;
    noobj += is_obj ? 0.f : cd;
  }

  // Wave (64-lane) butterfly reduction.
#pragma unroll
  for (int off = 32; off > 0; off >>= 1) {
    box   += __shfl_down(box, off);
    obj   += __shfl_down(obj, off);
    noobj += __shfl_down(noobj, off);
  }

  __shared__ float s[3][4];  // 4 waves per 256-thread block
  const int lane = threadIdx.x & 63;
  const int wid = threadIdx.x >> 6;
  if (lane == 0) {
    s[0][wid] = box;
    s[1][wid] = obj;
    s[2][wid] = noobj;
  }
  __syncthreads();
  if (threadIdx.x == 0) {
    float b = s[0][0] + s[0][1] + s[0][2] + s[0][3];
    float o = s[1][0] + s[1][1] + s[1][2] + s[1][3];
    float n = s[2][0] + s[2][1] + s[2][2] + s[2][3];
    atomicAdd(&out[1], LAMBDA_COORD * b);
    atomicAdd(&out[2], o);
    atomicAdd(&out[3], LAMBDA_NOOBJ * n);
  }
}

__global__ void yolo_loss_finalize(float* __restrict__ out) {
  out[0] = out[1] + out[2] + out[3];
}

extern "C" void kernel_launch(void* const* d_in, const int* in_sizes, int n_in,
                              void* d_out, int out_size, void* d_ws, size_t ws_size,
                              hipStream_t stream) {
  const float* pred = (const float*)d_in[0];
  const float* targ = (const float*)d_in[1];
  float* out = (float*)d_out;

  const int ncells = in_sizes[0] / 5;   // B*H*W = 6,553,600
  const int ngroups = ncells / 4;       // 1,638,400

  // d_out is poisoned once before timing and never re-zeroed between replays:
  // the kernel accumulates with atomics, so zero it ourselves every call.
  hipMemsetAsync(d_out, 0, out_size * sizeof(float), stream);

  const int block = 256;
  const int grid = 2048;  // grid-stride; ~8 blocks/CU worth of work
  yolo_loss_kernel<<<grid, block, 0, stream>>>(pred, targ, out, ngroups, ncells);
  yolo_loss_finalize<<<1, 1, 0, stream>>>(out);
}

// Round 2
// 88.546 us; speedup vs baseline: 1.1600x; 1.1600x over previous
//
#include <hip/hip_runtime.h>

#define LAMBDA_NOOBJ 0.5f
#define LAMBDA_COORD 5.0f

// Layout: cells of 5 floats (conf,x,y,h,w). Per-wave tile = 320 float4s
// (1280 floats = 256 cells) per input, staged coalesced into LDS via
// global_load_lds (5 x 1KB instructions per input), then read back per-cell
// as ds_read_b128 at 80B lane stride (conflict-free: stride/16=5 is odd).
__global__ __launch_bounds__(256) void yolo_loss_kernel(
    const float4* __restrict__ pred4,
    const float4* __restrict__ targ4,
    const float* __restrict__ pred,
    const float* __restrict__ targ,
    float* __restrict__ out,   // out[1]=box, out[2]=obj, out[3]=noobj
    int ntiles, int ncells) {
  // Per wave: 320 float4s pred + 320 float4s targ = 10 KB. 4 waves -> 40 KB.
  __shared__ float4 smem[2560];

  const int lane = threadIdx.x & 63;
  const int wid  = threadIdx.x >> 6;
  float4* wbase = smem + wid * 640;           // [0..319]=pred, [320..639]=targ

  const int nwaves   = (gridDim.x * blockDim.x) >> 6;
  const int wave_gid = ((blockIdx.x * blockDim.x + threadIdx.x) >> 6);

  float box = 0.f, obj = 0.f, noobj = 0.f;

  for (int tile = wave_gid; tile < ntiles; tile += nwaves) {
    const float4* pg = pred4 + (size_t)tile * 320;
    const float4* tg = targ4 + (size_t)tile * 320;

    // Stage: 5 rounds x 2 inputs, each 64 lanes x 16B contiguous.
#pragma unroll
    for (int r = 0; r < 5; ++r) {
      __builtin_amdgcn_global_load_lds(
          (const __attribute__((address_space(1))) void*)(pg + r * 64 + lane),
          (__attribute__((address_space(3))) void*)(wbase + r * 64), 16, 0, 0);
      __builtin_amdgcn_global_load_lds(
          (const __attribute__((address_space(1))) void*)(tg + r * 64 + lane),
          (__attribute__((address_space(3))) void*)(wbase + 320 + r * 64), 16, 0, 0);
    }
    asm volatile("s_waitcnt vmcnt(0)" ::: "memory");
    __builtin_amdgcn_sched_barrier(0);

    // Read own 4 cells (20 floats per input) from LDS.
    float p[20], t[20];
#pragma unroll
    for (int j = 0; j < 5; ++j) {
      float4 a = wbase[lane * 5 + j];
      float4 b = wbase[320 + lane * 5 + j];
      p[j * 4 + 0] = a.x; p[j * 4 + 1] = a.y; p[j * 4 + 2] = a.z; p[j * 4 + 3] = a.w;
      t[j * 4 + 0] = b.x; t[j * 4 + 1] = b.y; t[j * 4 + 2] = b.z; t[j * 4 + 3] = b.w;
    }
    // All ds_reads landed in registers before the next iteration's
    // global_load_lds may overwrite this wave's LDS region.
    asm volatile("s_waitcnt lgkmcnt(0)" ::: "memory");
    __builtin_amdgcn_sched_barrier(0);

#pragma unroll
    for (int c = 0; c < 4; ++c) {
      float c_t = t[c * 5];
      float cd = c_t - p[c * 5];
      cd *= cd;
      float bd = 0.f;
#pragma unroll
      for (int k = 1; k < 5; ++k) {
        float d = t[c * 5 + k] - p[c * 5 + k];
        bd += d * d;
      }
      bool is_obj = (c_t == 1.0f);
      box += is_obj ? bd : 0.f;
      obj += is_obj ? cd : 0.f;
      noobj += is_obj ? 0.f : cd;
    }
  }

  // Tail cells (ncells not covered by full tiles) — scalar path.
  const int tid = blockIdx.x * blockDim.x + threadIdx.x;
  const int stride = gridDim.x * blockDim.x;
  for (int c = ntiles * 256 + tid; c < ncells; c += stride) {
    const float* pc = pred + (size_t)c * 5;
    const float* tc = targ + (size_t)c * 5;
    float c_t = tc[0];
    float cd = c_t - pc[0];
    cd *= cd;
    float bd = 0.f;
#pragma unroll
    for (int k = 1; k < 5; ++k) {
      float d = tc[k] - pc[k];
      bd += d * d;
    }
    bool is_obj = (c_t == 1.0f);
    box += is_obj ? bd : 0.f;
    obj += is_obj ? cd : 0.f;
    noobj += is_obj ? 0.f : cd;
  }

  // Wave (64-lane) reduction.
#pragma unroll
  for (int off = 32; off > 0; off >>= 1) {
    box   += __shfl_down(box, off);
    obj   += __shfl_down(obj, off);
    noobj += __shfl_down(noobj, off);
  }

  __shared__ float s[3][4];
  if (lane == 0) {
    s[0][wid] = box;
    s[1][wid] = obj;
    s[2][wid] = noobj;
  }
  __syncthreads();
  if (threadIdx.x == 0) {
    float b = s[0][0] + s[0][1] + s[0][2] + s[0][3];
    float o = s[1][0] + s[1][1] + s[1][2] + s[1][3];
    float n = s[2][0] + s[2][1] + s[2][2] + s[2][3];
    atomicAdd(&out[1], LAMBDA_COORD * b);
    atomicAdd(&out[2], o);
    atomicAdd(&out[3], LAMBDA_NOOBJ * n);
  }
}

__global__ void yolo_loss_finalize(float* __restrict__ out) {
  out[0] = out[1] + out[2] + out[3];
}

extern "C" void kernel_launch(void* const* d_in, const int* in_sizes, int n_in,
                              void* d_out, int out_size, void* d_ws, size_t ws_size,
                              hipStream_t stream) {
  const float* pred = (const float*)d_in[0];
  const float* targ = (const float*)d_in[1];
  float* out = (float*)d_out;

  const int ncells = in_sizes[0] / 5;        // 6,553,600
  const int ntiles = ncells / 256;           // 25,600 (exact for this size)

  // d_out is poisoned once and never re-zeroed between replays; the kernel
  // accumulates with atomics, so zero it ourselves every call.
  hipMemsetAsync(d_out, 0, out_size * sizeof(float), stream);

  const int block = 256;
  const int grid = 1600;  // 6400 waves -> 4 tiles per wave
  yolo_loss_kernel<<<grid, block, 0, stream>>>(
      (const float4*)pred, (const float4*)targ, pred, targ, out, ntiles, ncells);
  yolo_loss_finalize<<<1, 1, 0, stream>>>(out);
}